// Round 1
// baseline (163.633 us; speedup 1.0000x reference)
//
#include <hip/hip_runtime.h>

// Dihedral2Coord: N=4096 molecules, K=128 dihedral steps, M=512 atoms.
// angles[k] = [k,k+1,k+2,k+3]; move_mask[k][m] = m > k+2 (both fixed by
// construction, so inputs 2 and 3 are ignored).
//
// Restructure: atom m's final position = M_{m-3}(pos0[m]) where M_k is the
// cumulative affine map of steps 0..k. At step k the four pivot atoms are:
//   p0=final[k], p1=final[k+1], p2=final[k+2]  (already final)
//   p3=M_{k-1}(pos0[k+3])                       (finalized this step)
// so the whole scan is a 128-step serial chain of {12-float affine state,
// 3 cached finals} per molecule, plus one affine apply per tail atom.

#define NK 128
#define NM 512
#define NMOL 4096
#define MPB 4     // molecules (chains) per block -> 1024 blocks, 1 wave each
#define TPB 64

struct V3f { float x, y, z; };

__device__ inline V3f v3sub(V3f a, V3f b) { return {a.x - b.x, a.y - b.y, a.z - b.z}; }
__device__ inline V3f v3cross(V3f a, V3f b) {
    return {a.y * b.z - a.z * b.y, a.z * b.x - a.x * b.z, a.x * b.y - a.y * b.x};
}
__device__ inline float v3dot(V3f a, V3f b) { return a.x * b.x + a.y * b.y + a.z * b.z; }

__global__ __launch_bounds__(TPB) void dihedral_chain_kernel(
    const float* __restrict__ theta,  // (NMOL, NK)
    const float* __restrict__ pos0,   // (NMOL, NM, 3)
    float* __restrict__ out)          // (NMOL, NM, 3)
{
    const int lane = threadIdx.x;
    const int mol  = blockIdx.x * MPB + lane;
    const bool active = (lane < MPB);

    // final cumulative affine per chain lane: rows of R, then t (12 floats), pad 13
    __shared__ float Ms[MPB][13];

    if (active) {
        const float* pb = pos0 + (size_t)mol * (NM * 3);
        float*       ob = out  + (size_t)mol * (NM * 3);
        const float* tb = theta + (size_t)mol * NK;

        V3f f0 = {pb[0], pb[1], pb[2]};   // final[k]
        V3f f1 = {pb[3], pb[4], pb[5]};   // final[k+1]
        V3f f2 = {pb[6], pb[7], pb[8]};   // final[k+2]
        // atoms 0..2 never move
        ob[0] = f0.x; ob[1] = f0.y; ob[2] = f0.z;
        ob[3] = f1.x; ob[4] = f1.y; ob[5] = f1.z;
        ob[6] = f2.x; ob[7] = f2.y; ob[8] = f2.z;

        // cumulative affine M (starts at identity)
        float r00 = 1.f, r01 = 0.f, r02 = 0.f;
        float r10 = 0.f, r11 = 1.f, r12 = 0.f;
        float r20 = 0.f, r21 = 0.f, r22 = 1.f;
        float tx = 0.f, ty = 0.f, tz = 0.f;

        // prefetch for step 0
        V3f   p3n = {pb[9], pb[10], pb[11]};  // pos0 atom 3
        float thn = tb[0];

        for (int k = 0; k < NK; ++k) {
            const V3f   p3raw = p3n;
            const float th    = thn;
            if (k + 1 < NK) {  // prefetch next step (atom k+4 <= 131 always valid)
                const float* pp = pb + (size_t)(k + 4) * 3;
                p3n = {pp[0], pp[1], pp[2]};
                thn = tb[k + 1];
            }

            float sth, cth;
            sincosf(th, &sth, &cth);

            // p3 = M(pos0[k+3])
            V3f p3 = {r00 * p3raw.x + r01 * p3raw.y + r02 * p3raw.z + tx,
                      r10 * p3raw.x + r11 * p3raw.y + r12 * p3raw.z + ty,
                      r20 * p3raw.x + r21 * p3raw.y + r22 * p3raw.z + tz};

            // dihedral geometry
            V3f rIJ = v3sub(f1, f0);
            V3f rJK = v3sub(f2, f1);
            V3f rKL = v3sub(p3, f2);
            V3f n1 = v3cross(rIJ, rJK);
            V3f n2 = v3cross(rJK, rKL);
            V3f mm = v3cross(n1, rJK);
            float dmn = v3dot(mm, n2);
            float dnn = v3dot(n1, n2);
            float Lm = v3dot(mm, mm);
            float L1 = v3dot(n1, n1);
            float L2 = v3dot(n2, n2);

            // sin/cos of current dihedral phi (renormalized so that
            // (cphi,sphi) == (cos,sin)(atan2(sin_arg,cos_arg)) up to ulps)
            float sphi = dmn * rsqrtf(Lm * L2);
            float cphi = dnn * rsqrtf(L1 * L2);
            float rn = rsqrtf(sphi * sphi + cphi * cphi);
            sphi *= rn;
            cphi *= rn;

            // angle-sum: values = theta + phi
            float c = cth * cphi - sth * sphi;
            float s = sth * cphi + cth * sphi;

            // rotation axis = normalize(rJK)  (ref: d / max(|d|,1e-12))
            float Ljk  = v3dot(rJK, rJK);
            float inva = rsqrtf(fmaxf(Ljk, 1e-24f));
            float ax = rJK.x * inva, ay = rJK.y * inva, az = rJK.z * inva;

            // Rodrigues
            float t = 1.0f - c;
            float sax = s * ax, say = s * ay, saz = s * az;
            float tax = t * ax, tay = t * ay, taz = t * az;
            float R00 = tax * ax + c,   R01 = tax * ay - saz, R02 = tax * az + say;
            float R10 = tay * ax + saz, R11 = tay * ay + c,   R12 = tay * az - sax;
            float R20 = taz * ax - say, R21 = taz * ay + sax, R22 = taz * az + c;

            // begin = f1; final[k+3] = R*(p3-begin)+begin
            V3f v = v3sub(p3, f1);
            V3f nf = {R00 * v.x + R01 * v.y + R02 * v.z + f1.x,
                      R10 * v.x + R11 * v.y + R12 * v.z + f1.y,
                      R20 * v.x + R21 * v.y + R22 * v.z + f1.z};

            // compose M' = A o M:  R' = R*Rm ; t' = R*(tm - b) + b
            float m00 = R00 * r00 + R01 * r10 + R02 * r20;
            float m01 = R00 * r01 + R01 * r11 + R02 * r21;
            float m02 = R00 * r02 + R01 * r12 + R02 * r22;
            float m10 = R10 * r00 + R11 * r10 + R12 * r20;
            float m11 = R10 * r01 + R11 * r11 + R12 * r21;
            float m12 = R10 * r02 + R11 * r12 + R12 * r22;
            float m20 = R20 * r00 + R21 * r10 + R22 * r20;
            float m21 = R20 * r01 + R21 * r11 + R22 * r21;
            float m22 = R20 * r02 + R21 * r12 + R22 * r22;
            float wx = tx - f1.x, wy = ty - f1.y, wz = tz - f1.z;
            float ntx = R00 * wx + R01 * wy + R02 * wz + f1.x;
            float nty = R10 * wx + R11 * wy + R12 * wz + f1.y;
            float ntz = R20 * wx + R21 * wy + R22 * wz + f1.z;
            r00 = m00; r01 = m01; r02 = m02;
            r10 = m10; r11 = m11; r12 = m12;
            r20 = m20; r21 = m21; r22 = m22;
            tx = ntx; ty = nty; tz = ntz;

            // emit final position of atom k+3
            float* op = ob + (size_t)(k + 3) * 3;
            op[0] = nf.x; op[1] = nf.y; op[2] = nf.z;

            // slide window of finals
            f0 = f1; f1 = f2; f2 = nf;
        }

        Ms[lane][0] = r00; Ms[lane][1] = r01; Ms[lane][2] = r02;
        Ms[lane][3] = r10; Ms[lane][4] = r11; Ms[lane][5] = r12;
        Ms[lane][6] = r20; Ms[lane][7] = r21; Ms[lane][8] = r22;
        Ms[lane][9] = tx;  Ms[lane][10] = ty; Ms[lane][11] = tz;
    }
    __syncthreads();

    // tail atoms m in [NK+3, NM): out = M_{K-1}(pos0[m]), block-cooperative,
    // coalesced 12B/lane
    for (int j = 0; j < MPB; ++j) {
        const int mol2 = blockIdx.x * MPB + j;
        const float* pb = pos0 + (size_t)mol2 * (NM * 3);
        float*       ob = out  + (size_t)mol2 * (NM * 3);
        const float a00 = Ms[j][0], a01 = Ms[j][1], a02 = Ms[j][2];
        const float a10 = Ms[j][3], a11 = Ms[j][4], a12 = Ms[j][5];
        const float a20 = Ms[j][6], a21 = Ms[j][7], a22 = Ms[j][8];
        const float bx = Ms[j][9], by = Ms[j][10], bz = Ms[j][11];
        for (int m = NK + 3 + lane; m < NM; m += TPB) {
            const float* p = pb + (size_t)m * 3;
            const float x = p[0], y = p[1], z = p[2];
            float* o = ob + (size_t)m * 3;
            o[0] = a00 * x + a01 * y + a02 * z + bx;
            o[1] = a10 * x + a11 * y + a12 * z + by;
            o[2] = a20 * x + a21 * y + a22 * z + bz;
        }
    }
}

extern "C" void kernel_launch(void* const* d_in, const int* in_sizes, int n_in,
                              void* d_out, int out_size, void* d_ws, size_t ws_size,
                              hipStream_t stream) {
    const float* theta = (const float*)d_in[0];  // input (N,K) fp32
    const float* pos0  = (const float*)d_in[1];  // pos0 (N,M,3) fp32
    float* out = (float*)d_out;                  // (N,M,3) fp32
    dihedral_chain_kernel<<<NMOL / MPB, TPB, 0, stream>>>(theta, pos0, out);
}

// Round 2
// 19.566 us; speedup vs baseline: 8.3632x; 8.3632x over previous
//
#include <hip/hip_runtime.h>

// Dihedral2Coord — prefix-scan formulation.
//
// Reference: sequential scan over k=0..127; step k rotates atoms m>k+2 about
// the (world-frame) bond axis atom[k+1]->atom[k+2] by angle theta_k + phi_k,
// where phi_k is the current dihedral of atoms k..k+3.
//
// Restructure:
//  (1) final[m] = M_{m-3}(pos0[m]) with M_k = A_k∘...∘A_0 (world rotations).
//  (2) At step k, the four pivot points are all M_{k-1}-images of
//      pos0[k..k+3] (atoms k,k+1 lie on the axes of intervening steps ->
//      fixed points), and dihedrals are rigid-invariant, so
//      phi_k = dihedral(pos0[k..k+3])  -- no serial dependency.
//  (3) A_k = M_{k-1} ∘ B_k ∘ M_{k-1}^{-1} where B_k is the LOCAL-frame
//      rotation (angle theta_k+phi_k, axis through pos0[k+1] along
//      pos0[k+2]-pos0[k+1]).  Hence M_k = B_0∘B_1∘...∘B_k : an associative
//      affine prefix product -> parallel scan, depth log2(128)=7.

#define NK 128
#define NM 512
#define NMOL 4096
#define TPB 128   // one molecule per block, thread k owns step k

#define COMPOSE_QP()                                                     \
    do {                                                                 \
        float n00=q00*p00+q01*p10+q02*p20;                               \
        float n01=q00*p01+q01*p11+q02*p21;                               \
        float n02=q00*p02+q01*p12+q02*p22;                               \
        float n10=q10*p00+q11*p10+q12*p20;                               \
        float n11=q10*p01+q11*p11+q12*p21;                               \
        float n12=q10*p02+q11*p12+q12*p22;                               \
        float n20=q20*p00+q21*p10+q22*p20;                               \
        float n21=q20*p01+q21*p11+q22*p21;                               \
        float n22=q20*p02+q21*p12+q22*p22;                               \
        float ntx=q00*ptx+q01*pty+q02*ptz+qtx;                           \
        float nty=q10*ptx+q11*pty+q12*ptz+qty;                           \
        float ntz=q20*ptx+q21*pty+q22*ptz+qtz;                           \
        p00=n00;p01=n01;p02=n02;p10=n10;p11=n11;p12=n12;                 \
        p20=n20;p21=n21;p22=n22;ptx=ntx;pty=nty;ptz=ntz;                 \
    } while (0)

__global__ __launch_bounds__(TPB) void dihedral_scan_kernel(
    const float* __restrict__ theta,  // (NMOL, NK)
    const float* __restrict__ pos0,   // (NMOL, NM, 3)
    float* __restrict__ out)          // (NMOL, NM, 3)
{
    const int tid = threadIdx.x;
    const int mol = blockIdx.x;
    const float* __restrict__ pb = pos0 + (size_t)mol * (NM * 3);
    float*       __restrict__ ob = out  + (size_t)mol * (NM * 3);

    __shared__ float sA[(NK + 3) * 3];  // atoms 0..130
    __shared__ float sT[12];            // wave-0 scan total
    __shared__ float sF[12];            // P_127

    for (int i = tid; i < (NK + 3) * 3; i += TPB) sA[i] = pb[i];
    const float th = theta[(size_t)mol * NK + tid];
    __syncthreads();

    // ---- phase 1: build B_k from local (pos0) geometry, fully parallel ----
    const float* ap = &sA[tid * 3];
    const float a0x = ap[0], a0y = ap[1],  a0z = ap[2];
    const float a1x = ap[3], a1y = ap[4],  a1z = ap[5];
    const float a2x = ap[6], a2y = ap[7],  a2z = ap[8];
    const float a3x = ap[9], a3y = ap[10], a3z = ap[11];

    const float ijx = a1x - a0x, ijy = a1y - a0y, ijz = a1z - a0z;
    const float jkx = a2x - a1x, jky = a2y - a1y, jkz = a2z - a1z;
    const float klx = a3x - a2x, kly = a3y - a2y, klz = a3z - a2z;
    const float n1x = ijy*jkz - ijz*jky, n1y = ijz*jkx - ijx*jkz, n1z = ijx*jky - ijy*jkx;
    const float n2x = jky*klz - jkz*kly, n2y = jkz*klx - jkx*klz, n2z = jkx*kly - jky*klx;
    const float mx  = n1y*jkz - n1z*jky, my  = n1z*jkx - n1x*jkz, mz  = n1x*jky - n1y*jkx;
    const float dmn = mx*n2x + my*n2y + mz*n2z;
    const float dnn = n1x*n2x + n1y*n2y + n1z*n2z;
    const float Lm  = mx*mx + my*my + mz*mz;
    const float L1  = n1x*n1x + n1y*n1y + n1z*n1z;
    const float L2  = n2x*n2x + n2y*n2y + n2z*n2z;

    // (cphi,sphi) == (cos,sin)(atan2(sin_arg,cos_arg)) up to ulps
    float sphi = dmn * rsqrtf(Lm * L2);
    float cphi = dnn * rsqrtf(L1 * L2);
    const float rn = rsqrtf(sphi * sphi + cphi * cphi);
    sphi *= rn; cphi *= rn;
    float sth, cth;
    sincosf(th, &sth, &cth);
    const float c = cth * cphi - sth * sphi;   // cos(theta + phi)
    const float s = sth * cphi + cth * sphi;   // sin(theta + phi)

    const float Ljk  = jkx*jkx + jky*jky + jkz*jkz;
    const float inva = rsqrtf(fmaxf(Ljk, 1e-24f));
    const float ax = jkx * inva, ay = jky * inva, az = jkz * inva;

    // Rodrigues; affine x -> P x + pt  with pt = begin - R*begin, begin = a1
    const float t1 = 1.0f - c;
    float p00 = t1*ax*ax + c,    p01 = t1*ax*ay - s*az, p02 = t1*ax*az + s*ay;
    float p10 = t1*ay*ax + s*az, p11 = t1*ay*ay + c,    p12 = t1*ay*az - s*ax;
    float p20 = t1*az*ax - s*ay, p21 = t1*az*ay + s*ax, p22 = t1*az*az + c;
    float ptx = a1x - (p00*a1x + p01*a1y + p02*a1z);
    float pty = a1y - (p10*a1x + p11*a1y + p12*a1z);
    float ptz = a1z - (p20*a1x + p21*a1y + p22*a1z);

    // ---- phase 2: inclusive scan  P_k = B_0∘...∘B_k ----
    const int lane = tid & 63;
    #pragma unroll
    for (int off = 1; off < 64; off <<= 1) {
        const float q00 = __shfl_up(p00, off, 64), q01 = __shfl_up(p01, off, 64), q02 = __shfl_up(p02, off, 64);
        const float q10 = __shfl_up(p10, off, 64), q11 = __shfl_up(p11, off, 64), q12 = __shfl_up(p12, off, 64);
        const float q20 = __shfl_up(p20, off, 64), q21 = __shfl_up(p21, off, 64), q22 = __shfl_up(p22, off, 64);
        const float qtx = __shfl_up(ptx, off, 64), qty = __shfl_up(pty, off, 64), qtz = __shfl_up(ptz, off, 64);
        if (lane >= off) { COMPOSE_QP(); }
    }
    if (tid == 63) {
        sT[0]=p00; sT[1]=p01; sT[2]=p02; sT[3]=p10; sT[4]=p11; sT[5]=p12;
        sT[6]=p20; sT[7]=p21; sT[8]=p22; sT[9]=ptx; sT[10]=pty; sT[11]=ptz;
    }
    __syncthreads();
    if (tid >= 64) {  // prepend wave-0 total
        const float q00=sT[0], q01=sT[1], q02=sT[2];
        const float q10=sT[3], q11=sT[4], q12=sT[5];
        const float q20=sT[6], q21=sT[7], q22=sT[8];
        const float qtx=sT[9], qty=sT[10], qtz=sT[11];
        COMPOSE_QP();
    }

    // ---- phase 3: outputs ----
    // atom k+3 = P_k(pos0[k+3])
    {
        const float ox = p00*a3x + p01*a3y + p02*a3z + ptx;
        const float oy = p10*a3x + p11*a3y + p12*a3z + pty;
        const float oz = p20*a3x + p21*a3y + p22*a3z + ptz;
        float* op = ob + (size_t)(tid + 3) * 3;
        op[0] = ox; op[1] = oy; op[2] = oz;
    }
    if (tid < 9) ob[tid] = sA[tid];  // atoms 0..2 never move
    if (tid == 127) {
        sF[0]=p00; sF[1]=p01; sF[2]=p02; sF[3]=p10; sF[4]=p11; sF[5]=p12;
        sF[6]=p20; sF[7]=p21; sF[8]=p22; sF[9]=ptx; sF[10]=pty; sF[11]=ptz;
    }
    __syncthreads();

    // tail atoms m in [131, 512): out = P_127(pos0[m])
    const float f00=sF[0], f01=sF[1], f02=sF[2];
    const float f10=sF[3], f11=sF[4], f12=sF[5];
    const float f20=sF[6], f21=sF[7], f22=sF[8];
    const float ftx=sF[9], fty=sF[10], ftz=sF[11];
    for (int mi = NK + 3 + tid; mi < NM; mi += TPB) {
        const float x = pb[mi*3 + 0], y = pb[mi*3 + 1], z = pb[mi*3 + 2];
        float* op = ob + (size_t)mi * 3;
        op[0] = f00*x + f01*y + f02*z + ftx;
        op[1] = f10*x + f11*y + f12*z + fty;
        op[2] = f20*x + f21*y + f22*z + ftz;
    }
}

extern "C" void kernel_launch(void* const* d_in, const int* in_sizes, int n_in,
                              void* d_out, int out_size, void* d_ws, size_t ws_size,
                              hipStream_t stream) {
    const float* theta = (const float*)d_in[0];  // input (N,K) fp32
    const float* pos0  = (const float*)d_in[1];  // pos0 (N,M,3) fp32
    float* out = (float*)d_out;                  // (N,M,3) fp32
    dihedral_scan_kernel<<<NMOL, TPB, 0, stream>>>(theta, pos0, out);
}

// Round 3
// 18.802 us; speedup vs baseline: 8.7030x; 1.0406x over previous
//
#include <hip/hip_runtime.h>

// Dihedral2Coord — prefix-scan formulation, fully float4-vectorized I/O.
//
//  (1) final[m] = M_{m-3}(pos0[m]); M_k = B_0∘B_1∘...∘B_k where B_k is the
//      LOCAL-frame rotation (dihedrals are rigid-invariant, so phi_k comes
//      from pos0 alone) -> associative affine prefix scan, depth 7.
//  (2) All global traffic is 16B-aligned float4: pos0[0..131] in as 99 f4,
//      final[0..131] staged in LDS and out as 99 f4, tail atoms 132..511 as
//      95 tasks x {3 f4 in, 4 transforms, 3 f4 out}.

#define NK 128
#define NM 512
#define NMOL 4096
#define TPB 128   // one molecule per block, thread k owns step k

#define COMPOSE_QP()                                                     \
    do {                                                                 \
        float n00=q00*p00+q01*p10+q02*p20;                               \
        float n01=q00*p01+q01*p11+q02*p21;                               \
        float n02=q00*p02+q01*p12+q02*p22;                               \
        float n10=q10*p00+q11*p10+q12*p20;                               \
        float n11=q10*p01+q11*p11+q12*p21;                               \
        float n12=q10*p02+q11*p12+q12*p22;                               \
        float n20=q20*p00+q21*p10+q22*p20;                               \
        float n21=q20*p01+q21*p11+q22*p21;                               \
        float n22=q20*p02+q21*p12+q22*p22;                               \
        float ntx=q00*ptx+q01*pty+q02*ptz+qtx;                           \
        float nty=q10*ptx+q11*pty+q12*ptz+qty;                           \
        float ntz=q20*ptx+q21*pty+q22*ptz+qtz;                           \
        p00=n00;p01=n01;p02=n02;p10=n10;p11=n11;p12=n12;                 \
        p20=n20;p21=n21;p22=n22;ptx=ntx;pty=nty;ptz=ntz;                 \
    } while (0)

__global__ __launch_bounds__(TPB) void dihedral_scan_kernel(
    const float* __restrict__ theta,  // (NMOL, NK)
    const float* __restrict__ pos0,   // (NMOL, NM, 3)
    float* __restrict__ out)          // (NMOL, NM, 3)
{
    const int tid = threadIdx.x;
    const int mol = blockIdx.x;
    const float* __restrict__ pb = pos0 + (size_t)mol * (NM * 3);
    float*       __restrict__ ob = out  + (size_t)mol * (NM * 3);
    const float4* __restrict__ pb4 = (const float4*)pb;
    float4*       __restrict__ ob4 = (float4*)ob;

    __shared__ float sA[396];    // pos0 atoms 0..131
    __shared__ float sO[396];    // final atoms 0..131
    __shared__ float sT[12];     // wave-0 scan total
    __shared__ float sF[12];     // P_127

    if (tid < 99) ((float4*)sA)[tid] = pb4[tid];
    const float th = theta[(size_t)mol * NK + tid];
    __syncthreads();

    // ---- phase 1: build B_k from local (pos0) geometry, fully parallel ----
    const float* ap = &sA[tid * 3];
    const float a0x = ap[0], a0y = ap[1],  a0z = ap[2];
    const float a1x = ap[3], a1y = ap[4],  a1z = ap[5];
    const float a2x = ap[6], a2y = ap[7],  a2z = ap[8];
    const float a3x = ap[9], a3y = ap[10], a3z = ap[11];

    const float ijx = a1x - a0x, ijy = a1y - a0y, ijz = a1z - a0z;
    const float jkx = a2x - a1x, jky = a2y - a1y, jkz = a2z - a1z;
    const float klx = a3x - a2x, kly = a3y - a2y, klz = a3z - a2z;
    const float n1x = ijy*jkz - ijz*jky, n1y = ijz*jkx - ijx*jkz, n1z = ijx*jky - ijy*jkx;
    const float n2x = jky*klz - jkz*kly, n2y = jkz*klx - jkx*klz, n2z = jkx*kly - jky*klx;
    const float mx  = n1y*jkz - n1z*jky, my  = n1z*jkx - n1x*jkz, mz  = n1x*jky - n1y*jkx;
    const float dmn = mx*n2x + my*n2y + mz*n2z;
    const float dnn = n1x*n2x + n1y*n2y + n1z*n2z;
    const float Lm  = mx*mx + my*my + mz*mz;
    const float L1  = n1x*n1x + n1y*n1y + n1z*n1z;
    const float L2  = n2x*n2x + n2y*n2y + n2z*n2z;

    // (cphi,sphi) == (cos,sin)(atan2(sin_arg,cos_arg)) up to ulps
    float sphi = dmn * rsqrtf(Lm * L2);
    float cphi = dnn * rsqrtf(L1 * L2);
    const float rn = rsqrtf(sphi * sphi + cphi * cphi);
    sphi *= rn; cphi *= rn;
    float sth, cth;
    sincosf(th, &sth, &cth);
    const float c = cth * cphi - sth * sphi;   // cos(theta + phi)
    const float s = sth * cphi + cth * sphi;   // sin(theta + phi)

    const float Ljk  = jkx*jkx + jky*jky + jkz*jkz;
    const float inva = rsqrtf(fmaxf(Ljk, 1e-24f));
    const float ax = jkx * inva, ay = jky * inva, az = jkz * inva;

    // Rodrigues; affine x -> P x + pt  with pt = begin - R*begin, begin = a1
    const float t1 = 1.0f - c;
    float p00 = t1*ax*ax + c,    p01 = t1*ax*ay - s*az, p02 = t1*ax*az + s*ay;
    float p10 = t1*ay*ax + s*az, p11 = t1*ay*ay + c,    p12 = t1*ay*az - s*ax;
    float p20 = t1*az*ax - s*ay, p21 = t1*az*ay + s*ax, p22 = t1*az*az + c;
    float ptx = a1x - (p00*a1x + p01*a1y + p02*a1z);
    float pty = a1y - (p10*a1x + p11*a1y + p12*a1z);
    float ptz = a1z - (p20*a1x + p21*a1y + p22*a1z);

    // ---- phase 2: inclusive scan  P_k = B_0∘...∘B_k ----
    const int lane = tid & 63;
    #pragma unroll
    for (int off = 1; off < 64; off <<= 1) {
        const float q00 = __shfl_up(p00, off, 64), q01 = __shfl_up(p01, off, 64), q02 = __shfl_up(p02, off, 64);
        const float q10 = __shfl_up(p10, off, 64), q11 = __shfl_up(p11, off, 64), q12 = __shfl_up(p12, off, 64);
        const float q20 = __shfl_up(p20, off, 64), q21 = __shfl_up(p21, off, 64), q22 = __shfl_up(p22, off, 64);
        const float qtx = __shfl_up(ptx, off, 64), qty = __shfl_up(pty, off, 64), qtz = __shfl_up(ptz, off, 64);
        if (lane >= off) { COMPOSE_QP(); }
    }
    if (tid == 63) {
        sT[0]=p00; sT[1]=p01; sT[2]=p02; sT[3]=p10; sT[4]=p11; sT[5]=p12;
        sT[6]=p20; sT[7]=p21; sT[8]=p22; sT[9]=ptx; sT[10]=pty; sT[11]=ptz;
    }
    __syncthreads();
    if (tid >= 64) {  // prepend wave-0 total
        const float q00=sT[0], q01=sT[1], q02=sT[2];
        const float q10=sT[3], q11=sT[4], q12=sT[5];
        const float q20=sT[6], q21=sT[7], q22=sT[8];
        const float qtx=sT[9], qty=sT[10], qtz=sT[11];
        COMPOSE_QP();
    }

    // ---- phase 3: stage final atoms 0..131 in LDS ----
    {   // atom tid+3 = P_tid(pos0[tid+3])
        float* op = &sO[(tid + 3) * 3];
        op[0] = p00*a3x + p01*a3y + p02*a3z + ptx;
        op[1] = p10*a3x + p11*a3y + p12*a3z + pty;
        op[2] = p20*a3x + p21*a3y + p22*a3z + ptz;
    }
    if (tid < 9) sO[tid] = sA[tid];  // atoms 0..2 never move
    if (tid == 127) {
        sF[0]=p00; sF[1]=p01; sF[2]=p02; sF[3]=p10; sF[4]=p11; sF[5]=p12;
        sF[6]=p20; sF[7]=p21; sF[8]=p22; sF[9]=ptx; sF[10]=pty; sF[11]=ptz;
        // atom 131 = P_127(pos0[131])
        const float x = sA[393], y = sA[394], z = sA[395];
        sO[393] = p00*x + p01*y + p02*z + ptx;
        sO[394] = p10*x + p11*y + p12*z + pty;
        sO[395] = p20*x + p21*y + p22*z + ptz;
    }
    __syncthreads();

    // ---- phase 4: vectorized output ----
    if (tid < 99) ob4[tid] = ((const float4*)sO)[tid];

    // tail atoms 132..511: 95 tasks x 4 atoms (3 aligned float4 each way)
    const float f00=sF[0], f01=sF[1], f02=sF[2];
    const float f10=sF[3], f11=sF[4], f12=sF[5];
    const float f20=sF[6], f21=sF[7], f22=sF[8];
    const float ftx=sF[9], fty=sF[10], ftz=sF[11];
    if (tid < 95) {
        const int b4 = 99 + 3 * tid;
        const float4 va = pb4[b4], vb = pb4[b4 + 1], vc = pb4[b4 + 2];
        const float x0 = va.x, y0 = va.y, z0 = va.z;
        const float x1 = va.w, y1 = vb.x, z1 = vb.y;
        const float x2 = vb.z, y2 = vb.w, z2 = vc.x;
        const float x3 = vc.y, y3 = vc.z, z3 = vc.w;
        const float X0 = f00*x0 + f01*y0 + f02*z0 + ftx;
        const float Y0 = f10*x0 + f11*y0 + f12*z0 + fty;
        const float Z0 = f20*x0 + f21*y0 + f22*z0 + ftz;
        const float X1 = f00*x1 + f01*y1 + f02*z1 + ftx;
        const float Y1 = f10*x1 + f11*y1 + f12*z1 + fty;
        const float Z1 = f20*x1 + f21*y1 + f22*z1 + ftz;
        const float X2 = f00*x2 + f01*y2 + f02*z2 + ftx;
        const float Y2 = f10*x2 + f11*y2 + f12*z2 + fty;
        const float Z2 = f20*x2 + f21*y2 + f22*z2 + ftz;
        const float X3 = f00*x3 + f01*y3 + f02*z3 + ftx;
        const float Y3 = f10*x3 + f11*y3 + f12*z3 + fty;
        const float Z3 = f20*x3 + f21*y3 + f22*z3 + ftz;
        float4 o0, o1, o2;
        o0.x = X0; o0.y = Y0; o0.z = Z0; o0.w = X1;
        o1.x = Y1; o1.y = Z1; o1.z = X2; o1.w = Y2;
        o2.x = Z2; o2.y = X3; o2.z = Y3; o2.w = Z3;
        ob4[b4] = o0; ob4[b4 + 1] = o1; ob4[b4 + 2] = o2;
    }
}

extern "C" void kernel_launch(void* const* d_in, const int* in_sizes, int n_in,
                              void* d_out, int out_size, void* d_ws, size_t ws_size,
                              hipStream_t stream) {
    const float* theta = (const float*)d_in[0];  // input (N,K) fp32
    const float* pos0  = (const float*)d_in[1];  // pos0 (N,M,3) fp32
    float* out = (float*)d_out;                  // (N,M,3) fp32
    dihedral_scan_kernel<<<NMOL, TPB, 0, stream>>>(theta, pos0, out);
}